// Round 8
// baseline (229.134 us; speedup 1.0000x reference)
//
#include <hip/hip_runtime.h>

#define NPTS 65536          // B*N = 32*2048
#define HH 256
#define DIN 131
#define LAT 128
#define STEPS 5
#define DT 0.2f
#define P 32                // points per block

typedef unsigned int uint;
typedef unsigned short ushort;
typedef __attribute__((ext_vector_type(8))) short short8;
typedef __attribute__((ext_vector_type(4))) float floatx4;

__device__ __forceinline__ float tanh_fast(float x) {
    // tanh(x) = 1 - 2/(exp2(2x*log2e)+1); exact at both saturated ends.
    float e = __builtin_amdgcn_exp2f(x * 2.8853900817779268f);
    return 1.0f - 2.0f * __builtin_amdgcn_rcpf(e + 1.0f);
}

__device__ __forceinline__ ushort f2bf(float f) {
    uint u = __builtin_bit_cast(uint, f);
    u += 0x7fffu + ((u >> 16) & 1u);   // RNE
    return (ushort)(u >> 16);
}

// pack two f32 -> 2x bf16 (RNE) in one instruction; lo -> bits[15:0]
__device__ __forceinline__ uint cvt_pk_bf16(float lo, float hi) {
    uint r;
    asm("v_cvt_pk_bf16_f32 %0, %1, %2" : "=v"(r) : "v"(lo), "v"(hi));
    return r;
}

// 16-lane row sum via DPP row_shr chain (VALU pipe, no LDS traffic).
// Result valid in lane 15 of each 16-lane row. (Harness-verified r3-r7.)
__device__ __forceinline__ float dpp_sum16(float x) {
    int t;
    t = __builtin_amdgcn_update_dpp(0, __builtin_bit_cast(int, x), 0x111, 0xf, 0xf, true);
    x += __builtin_bit_cast(float, t);
    t = __builtin_amdgcn_update_dpp(0, __builtin_bit_cast(int, x), 0x112, 0xf, 0xf, true);
    x += __builtin_bit_cast(float, t);
    t = __builtin_amdgcn_update_dpp(0, __builtin_bit_cast(int, x), 0x114, 0xf, 0xf, true);
    x += __builtin_bit_cast(float, t);
    t = __builtin_amdgcn_update_dpp(0, __builtin_bit_cast(int, x), 0x118, 0xf, 0xf, true);
    x += __builtin_bit_cast(float, t);
    return x;
}

// ---- prep (unchanged from r7):
//  a1[b][h] = b1[h] + sum_l z[b][l]*W1[h][3+l]   (t=0 bias)
//  rs[h] = sum_l W1[h][3+l]
//  wsw = W2 as bf16 B-fragments
__global__ void prep_kernel(const float* __restrict__ z, const float* __restrict__ W1,
                            const float* __restrict__ b1, const float* __restrict__ W2,
                            float* __restrict__ a1, float* __restrict__ rsv,
                            ushort* __restrict__ wsw)
{
    int tid = blockIdx.x * 256 + threadIdx.x;
    if (tid < 8192) {
        int b = tid >> 8, h = tid & 255;
        const float* wrow = W1 + h * DIN;
        const float* zb = z + b * LAT;
        float s = b1[h], r = 0.f;
        for (int l = 0; l < LAT; ++l) { float wv = wrow[3 + l]; s += wv * zb[l]; r += wv; }
        a1[tid] = s;
        if (b == 0) rsv[h] = r;
    } else {
        int t = tid - 8192;                    // 0..8191
        int lane = t & 63, kt = (t >> 6) & 7, nt = t >> 9;
        int n = nt * 16 + (lane & 15);
        int k = kt * 32 + (lane >> 4) * 8;
        const float* src = W2 + n * HH + k;
        ushort* dst = wsw + t * 8;
        #pragma unroll
        for (int j = 0; j < 8; ++j) dst[j] = f2bf(src[j]);
    }
}

// PING-PONG PIPELINE (r8): the two 16-point half-tiles (rows 0-15 = group 0,
// rows 16-31 = group 1 of Vb) are independent: interval k runs
//   GEMM+epilogue(group k&1, step k>>1)  ||  phase-1(group (k&1)^1, step (k+1)>>1)
// in ONE basic block so the scheduler interleaves the MFMA stream with the
// independent VALU stream (r7 postmortem: VALU 94us + MFMA 55us SUMMED, not maxed).
// Hazards: every producer/consumer pair (Vb rows of g; XC[g] atomics) is separated
// by exactly one end-of-interval barrier; within an interval the two groups touch
// disjoint LDS. acc halves to [3][4]=48 regs (group is interval parity, not a dim).
__global__ __launch_bounds__(256, 2) void cnf_kernel(
        const float* __restrict__ xin, const float* __restrict__ W1,
        const float* __restrict__ b2, const float* __restrict__ W3,
        const float* __restrict__ b3, const float* __restrict__ osc,
        const float* __restrict__ a1, const float* __restrict__ rsv,
        const ushort* __restrict__ wsw, float* __restrict__ out)
{
    __shared__ __align__(16) ushort Vb[3 * P * HH];          // 49152 B
    __shared__ __align__(16) float4 XC[P];                   // 512 B: (x0, x1, c, -)

    const int tid = threadIdx.x;
    const int lane = tid & 63;
    const int w = tid >> 6;
    const int r15 = lane & 15;
    const int q = lane >> 4;
    const int blk = blockIdx.x;
    const int b = blk >> 6;                                  // 64 blocks per batch
    const int pbase = blk * P;
    const int hp = tid & 127;
    const int h0 = hp * 2;
    const int pst = tid >> 7;

    // per-thread layer-1 constants (own h-pair only)
    const float wa  = W1[h0 * DIN + 0],  wbv = W1[(h0 + 1) * DIN + 0];
    const float wc  = W1[h0 * DIN + 1],  wd  = W1[(h0 + 1) * DIN + 1];
    const float wta = W1[h0 * DIN + 2],  wtb = W1[(h0 + 1) * DIN + 2];
    const float ra  = rsv[h0],           rb  = rsv[h0 + 1];
    const float ba  = a1[b * HH + h0];                       // t=0 bias
    const float bb  = a1[b * HH + h0 + 1];

    if (tid < P) {
        int gp = pbase + tid;
        XC[tid] = (float4){xin[gp * 2 + 0], xin[gp * 2 + 1], 0.f, 0.f};
    }
    const float osdt = osc[0] * DT;
    const float ab0 = (w == 0) ? b3[0] * osdt : 0.f;         // b3 bias once/point/step
    const float ab1 = (w == 0) ? b3[1] * osdt : 0.f;
    float w30r[4], w31r[4], b2r[4];
    #pragma unroll
    for (int n = 0; n < 4; ++n) {
        int j = (w * 4 + n) * 16 + r15;                      // this lane's output column
        w30r[n] = W3[j];
        w31r[n] = W3[HH + j];
        b2r[n] = b2[j];
    }
    __syncthreads();

    const char* vrow = (const char*)Vb + r15 * 512;          // group -> +8192, v -> +16384
    const int xr = (r15 & 7) << 4;
    const ushort* wb_ = wsw + (size_t)(w * 4) * 4096 + (size_t)lane * 8;

    // ---- prologue: phase-1 of group 0, step 0 ----
    #pragma unroll
    for (int i = 0; i < 8; ++i) {
        int p = pst + 2 * i;                                 // group 0: p in [0,16)
        float4 xc = XC[p];
        float pa = ba + wa  * xc.x + wc * xc.y + ra * xc.z;
        float pb = bb + wbv * xc.x + wd * xc.y + rb * xc.z;
        float ha = tanh_fast(pa), hb = tanh_fast(pb);
        float ga = 1.f - ha * ha, gb = 1.f - hb * hb;
        char* dst = (char*)Vb + p * 512 + ((4 * hp) ^ ((p & 7) << 4));
        *(uint*)(dst)         = cvt_pk_bf16(ha,       hb);
        *(uint*)(dst + 16384) = cvt_pk_bf16(ga * wa,  gb * wbv);
        *(uint*)(dst + 32768) = cvt_pk_bf16(ga * wc,  gb * wd);
    }
    __syncthreads();

    // ---- 9 pipelined intervals + 1 drain interval (10 GEMMs = 2 groups x 5 steps) ----
    for (int k = 0; k < 10; ++k) {
        const int g = k & 1;                                 // GEMM/epilogue group
        const char* ap_base = vrow + g * 8192;

        floatx4 acc[3][4];
        #pragma unroll
        for (int v = 0; v < 3; ++v)
            #pragma unroll
            for (int n = 0; n < 4; ++n)
                acc[v][n] = (floatx4){0.f, 0.f, 0.f, 0.f};

        __builtin_amdgcn_s_setprio(1);
        #pragma unroll
        for (int kt = 0; kt < 8; ++kt) {
            const int boff = (kt * 64 + q * 16) ^ xr;        // swizzled K-slice byte offset
            const char* ap = ap_base + boff;
            short8 a0f = *(const short8*)(ap);
            short8 a1f = *(const short8*)(ap + 16384);
            short8 a2f = *(const short8*)(ap + 32768);
            #pragma unroll
            for (int n = 0; n < 4; ++n) {
                short8 bfr = *(const short8*)(wb_ + (size_t)(n * 8 + kt) * 512);
                acc[0][n] = __builtin_amdgcn_mfma_f32_16x16x32_bf16(a0f, bfr, acc[0][n], 0, 0, 0);
                acc[1][n] = __builtin_amdgcn_mfma_f32_16x16x32_bf16(a1f, bfr, acc[1][n], 0, 0, 0);
                acc[2][n] = __builtin_amdgcn_mfma_f32_16x16x32_bf16(a2f, bfr, acc[2][n], 0, 0, 0);
            }
        }
        __builtin_amdgcn_s_setprio(0);

        // ---- phase-1 of the OTHER group for its next step (independent of acc;
        //      scheduler interleaves this VALU stream with the MFMA stream above) ----
        if (k < 9) {
            const int sp = (k + 1) >> 1;                     // phase-1 step index
            const float fs = (float)sp * DT;
            const float pba = ba + wta * fs;
            const float pbb = bb + wtb * fs;
            const int pb0 = (g ^ 1) * 16;
            #pragma unroll
            for (int i = 0; i < 8; ++i) {
                int p = pb0 + pst + 2 * i;
                float4 xc = XC[p];
                float pa = pba + wa  * xc.x + wc * xc.y + ra * xc.z;
                float pb = pbb + wbv * xc.x + wd * xc.y + rb * xc.z;
                float ha = tanh_fast(pa), hb = tanh_fast(pb);
                float ga = 1.f - ha * ha, gb = 1.f - hb * hb;
                char* dst = (char*)Vb + p * 512 + ((4 * hp) ^ ((p & 7) << 4));
                *(uint*)(dst)         = cvt_pk_bf16(ha,       hb);
                *(uint*)(dst + 16384) = cvt_pk_bf16(ga * wa,  gb * wbv);
                *(uint*)(dst + 32768) = cvt_pk_bf16(ga * wc,  gb * wd);
            }
        }

        // ---- epilogue(g): h2/g2, W3 projection, DPP-reduce, atomic Euler update ----
        {
            float sv0[4] = {0,0,0,0}, sv1[4] = {0,0,0,0}, sdv[4] = {0,0,0,0};
            #pragma unroll
            for (int n = 0; n < 4; ++n) {
                const float w0 = w30r[n], w1 = w31r[n], bbj = b2r[n];
                #pragma unroll
                for (int r = 0; r < 4; ++r) {
                    float h2 = tanh_fast(acc[0][n][r] + bbj);
                    float g2 = 1.f - h2 * h2;
                    sv0[r] += h2 * w0;
                    sv1[r] += h2 * w1;
                    sdv[r] += g2 * (acc[1][n][r] * w0 + acc[2][n][r] * w1);
                }
            }
            #pragma unroll
            for (int r = 0; r < 4; ++r) {
                float ta = dpp_sum16(sv0[r]);
                float tb = dpp_sum16(sv1[r]);
                float td = dpp_sum16(sdv[r]);
                if (r15 == 15) {
                    int p = g * 16 + q * 4 + r;
                    atomicAdd(&XC[p].x, ta * osdt + ab0);    // ds_add_f32
                    atomicAdd(&XC[p].y, tb * osdt + ab1);
                    atomicAdd(&XC[p].z, td * osdt);
                }
            }
        }
        __syncthreads();                                     // orders Vb writes + XC atomics
    }

    if (tid < P) {
        int gp = pbase + tid;
        float4 xc = XC[tid];
        out[gp * 2 + 0] = xc.x;
        out[gp * 2 + 1] = xc.y;
        out[NPTS * 2 + gp] = xc.z;        // log_det
    }
}

extern "C" void kernel_launch(void* const* d_in, const int* in_sizes, int n_in,
                              void* d_out, int out_size, void* d_ws, size_t ws_size,
                              hipStream_t stream) {
    const float* x   = (const float*)d_in[0];
    const float* z   = (const float*)d_in[1];
    const float* W1  = (const float*)d_in[2];
    const float* b1  = (const float*)d_in[3];
    const float* W2  = (const float*)d_in[4];
    const float* b2  = (const float*)d_in[5];
    const float* W3  = (const float*)d_in[6];
    const float* b3  = (const float*)d_in[7];
    const float* osc = (const float*)d_in[8];

    // ws layout: a1 [8192 f] @0 | rs [256 f] @32768B | wsw [65536 bf16] @33792B (~165KB)
    float* a1  = (float*)d_ws;
    float* rsv = (float*)((char*)d_ws + 32768);
    ushort* wsw = (ushort*)((char*)d_ws + 33792);

    hipLaunchKernelGGL(prep_kernel, dim3(64), dim3(256), 0, stream, z, W1, b1, W2, a1, rsv, wsw);
    hipLaunchKernelGGL(cnf_kernel, dim3(2048), dim3(256), 0, stream,
                       x, W1, b2, W3, b3, osc, a1, rsv, wsw, (float*)d_out);
}